// Round 2
// baseline (990.351 us; speedup 1.0000x reference)
//
#include <hip/hip_runtime.h>

constexpr int   TH    = 8;     // TREE_HEIGHT
constexpr int   NNEG  = 8;     // N_NEG
constexpr int   HID   = 1024;  // HIDDEN
constexpr int   HALF  = 512;   // SINGLE_DIM
constexpr float SCR_F = 6.2831853071795864769f; // 2*pi

// One block per batch element, 128 threads (2 waves); thread t owns columns
// [4t,4t+4) of the 512-wide folded space. All row indices are block-uniform:
// forced into SGPRs via readfirstlane so each gather load is
// global_load_dwordx4 with scalar base + one shared voffset (4t*4B), hi half
// via +2048B. emb[p1] cancels algebraically (verified round 1, absmax 0).
__global__ __launch_bounds__(128)
void punish_kernel(const float* __restrict__ emb,
                   const int*   __restrict__ pos_path,
                   const int*   __restrict__ neg_path,
                   float*       __restrict__ partial)
{
    const int b = blockIdx.x;
    const int t = threadIdx.x;          // 0..127

    const int* __restrict__ pp = pos_path + b * (2 * TH);
    const int* __restrict__ np = neg_path + b * (NNEG * TH);

    // Uniform index fetch -> SGPRs (scalar addressing for all gathers)
    int p1[TH], p2[TH];
#pragma unroll
    for (int h = 0; h < TH; h++) {
        p1[h] = __builtin_amdgcn_readfirstlane(pp[h]);
        p2[h] = __builtin_amdgcn_readfirstlane(pp[TH + h]);
    }

    // diff_pos = max(8 - |p1 ∩ p2|, 1)  (scalar math, uniform)
    int inter_pos = 0;
#pragma unroll
    for (int i = 0; i < TH; i++) {
        bool f = false;
#pragma unroll
        for (int j = 0; j < TH; j++) f = f || (p1[i] == p2[j]);
        inter_pos += f ? 1 : 0;
    }
    const float diff_pos = fmaxf((float)(TH - inter_pos), 1.0f);

    // Sum of p2 rows, low+high halves folded
    float4 sp2 = {0.f, 0.f, 0.f, 0.f};
#pragma unroll
    for (int h = 0; h < TH; h++) {
        const float* row = emb + (size_t)(unsigned)p2[h] * HID;
        const float4 lo = *(const float4*)(row + 4 * t);
        const float4 hi = *(const float4*)(row + HALF + 4 * t);
        sp2.x += lo.x + hi.x;
        sp2.y += lo.y + hi.y;
        sp2.z += lo.z + hi.z;
        sp2.w += lo.w + hi.w;
    }

    float a[NNEG];
#pragma unroll
    for (int n = 0; n < NNEG; n++) {
        int ng[TH];
#pragma unroll
        for (int h = 0; h < TH; h++)
            ng[h] = __builtin_amdgcn_readfirstlane(np[n * TH + h]);

        int inter_n = 0;
#pragma unroll
        for (int i = 0; i < TH; i++) {
            bool f = false;
#pragma unroll
            for (int j = 0; j < TH; j++) f = f || (p1[i] == ng[j]);
            inter_n += f ? 1 : 0;
        }
        const int raw = TH - inter_n;   // diff_neg_raw
        // C[n] = (diff_pos - 1 - (raw==0)) * 2pi  (derivation verified R1)
        const float c = (diff_pos - 1.0f - (raw == 0 ? 1.0f : 0.0f)) * SCR_F;

        float4 sn = {0.f, 0.f, 0.f, 0.f};
#pragma unroll
        for (int h = 0; h < TH; h++) {
            const float* row = emb + (size_t)(unsigned)ng[h] * HID;
            const float4 lo = *(const float4*)(row + 4 * t);
            const float4 hi = *(const float4*)(row + HALF + 4 * t);
            sn.x += lo.x + hi.x;
            sn.y += lo.y + hi.y;
            sn.z += lo.z + hi.z;
            sn.w += lo.w + hi.w;
        }
        float vx = fmaxf(c + 0.5f * (sn.x - sp2.x), 0.f);
        float vy = fmaxf(c + 0.5f * (sn.y - sp2.y), 0.f);
        float vz = fmaxf(c + 0.5f * (sn.z - sp2.z), 0.f);
        float vw = fmaxf(c + 0.5f * (sn.w - sp2.w), 0.f);
        a[n] = vx * vx + vy * vy + vz * vz + vw * vw;
    }

    // Wave-64 butterfly reduce each of the 8 column-sums
#pragma unroll
    for (int n = 0; n < NNEG; n++) {
#pragma unroll
        for (int off = 32; off > 0; off >>= 1) {
            a[n] += __shfl_down(a[n], off, 64);
        }
    }

    __shared__ float s_red[2][NNEG];
    const int lane = t & 63;
    const int wid  = t >> 6;
    if (lane == 0) {
#pragma unroll
        for (int n = 0; n < NNEG; n++) s_red[wid][n] = a[n];
    }
    __syncthreads();

    if (t == 0) {
        float total = 0.f;
#pragma unroll
        for (int n = 0; n < NNEG; n++)
            total += sqrtf(s_red[0][n] + s_red[1][n]);
        partial[b] = total;   // no atomic; reduced by second kernel
    }
}

// Sum 2048 per-block partials -> out[0]
__global__ __launch_bounds__(256)
void reduce_kernel(const float* __restrict__ partial, float* __restrict__ out,
                   int n)
{
    const int t = threadIdx.x;
    float s = 0.f;
    for (int i = t; i < n; i += 256) s += partial[i];
#pragma unroll
    for (int off = 32; off > 0; off >>= 1) s += __shfl_down(s, off, 64);

    __shared__ float s_w[4];
    const int lane = t & 63, wid = t >> 6;
    if (lane == 0) s_w[wid] = s;
    __syncthreads();
    if (t == 0) out[0] = s_w[0] + s_w[1] + s_w[2] + s_w[3];
}

extern "C" void kernel_launch(void* const* d_in, const int* in_sizes, int n_in,
                              void* d_out, int out_size, void* d_ws, size_t ws_size,
                              hipStream_t stream) {
    const float* emb      = (const float*)d_in[0];
    const int*   pos_path = (const int*)d_in[1];
    const int*   neg_path = (const int*)d_in[2];
    float*       out      = (float*)d_out;
    float*       partial  = (float*)d_ws;   // BATCH floats of scratch

    const int BATCH = in_sizes[1] / (2 * TH);   // 2048

    punish_kernel<<<BATCH, 128, 0, stream>>>(emb, pos_path, neg_path, partial);
    reduce_kernel<<<1, 256, 0, stream>>>(partial, out, BATCH);
}